// Round 1
// baseline (478.184 us; speedup 1.0000x reference)
//
#include <hip/hip_runtime.h>
#include <math.h>

#define HW (128*128)
#define CIN2 66
#define NW_MAIN (594*64)   // transposed main weight  [(c*9+kk)*64 + o]
#define NW_OM   (594*27)   // transposed offset weight [(c*9+i)*27 + oc]

__global__ __launch_bounds__(256) void transpose_w(
    const float* __restrict__ weight, const float* __restrict__ w_om,
    float* __restrict__ wt, float* __restrict__ wmt)
{
    int t = blockIdx.x * 256 + threadIdx.x;
    if (t < NW_MAIN) {
        int o = t & 63, ck = t >> 6;
        wt[t] = weight[o * 594 + ck];
    }
    if (t < NW_OM) {
        int oc = t % 27, ck = t / 27;
        wmt[t] = w_om[oc * 594 + ck];
    }
}

// T = true: weights are transposed (contiguous fast dim = output channel)
template<bool T>
__global__ __launch_bounds__(256) void dcn_fused(
    const float* __restrict__ input,
    const float* __restrict__ wmain,   // T ? wt : weight
    const float* __restrict__ bias,
    const float* __restrict__ wom,     // T ? wmt : w_om
    const float* __restrict__ b_om,
    float* __restrict__ out)
{
    const int wo = blockIdx.x * 64 + threadIdx.x;   // 0..127
    const int ho = blockIdx.y * 4 + threadIdx.y;    // 0..127
    const int b  = blockIdx.z;
    const int p  = ho * 128 + wo;
    const float invH = 1.0f / 128.0f;

    const float* inb = input + (size_t)b * 64 * HW;

    // ---------------- Phase 1: offset-mask conv (3x3, 66 -> 27), zero pad ----
    float om[27];
#pragma unroll
    for (int oc = 0; oc < 27; ++oc) om[oc] = b_om[oc];

    for (int c = 0; c < 64; ++c) {
        const float* pc = inb + c * HW;
        float v[9];
#pragma unroll
        for (int kh = 0; kh < 3; ++kh) {
            int y = ho - 1 + kh;
            bool oky = (unsigned)y < 128u;
#pragma unroll
            for (int kw = 0; kw < 3; ++kw) {
                int x = wo - 1 + kw;
                bool ok = oky && ((unsigned)x < 128u);
                v[kh*3+kw] = ok ? pc[y * 128 + x] : 0.0f;
            }
        }
#pragma unroll
        for (int oc = 0; oc < 27; ++oc) {
#pragma unroll
            for (int i = 0; i < 9; ++i) {
                float w = T ? wom[(c*9 + i)*27 + oc] : wom[oc*594 + c*9 + i];
                om[oc] = fmaf(v[i], w, om[oc]);
            }
        }
    }
    // coordinate channels c=64 (y/H) and c=65 (x/W - 0.5), zero-padded
    {
        float v64[9], v65[9];
#pragma unroll
        for (int kh = 0; kh < 3; ++kh) {
            int y = ho - 1 + kh;
            bool oky = (unsigned)y < 128u;
#pragma unroll
            for (int kw = 0; kw < 3; ++kw) {
                int x = wo - 1 + kw;
                bool ok = oky && ((unsigned)x < 128u);
                v64[kh*3+kw] = ok ? y * invH : 0.0f;
                v65[kh*3+kw] = ok ? (x * invH - 0.5f) : 0.0f;
            }
        }
#pragma unroll
        for (int oc = 0; oc < 27; ++oc) {
#pragma unroll
            for (int i = 0; i < 9; ++i) {
                float wa = T ? wom[(64*9 + i)*27 + oc] : wom[oc*594 + 64*9 + i];
                float wb = T ? wom[(65*9 + i)*27 + oc] : wom[oc*594 + 65*9 + i];
                om[oc] = fmaf(v64[i], wa, om[oc]);
                om[oc] = fmaf(v65[i], wb, om[oc]);
            }
        }
    }

    // ---------------- outputs: idx and mask ----------------
    const float hg = ho * invH;
    const float wg = wo * invH - 0.5f;
    const float kh_i[9] = {-1,-1,-1, 0,0,0, 1,1,1};
    const float kw_i[9] = {-1,0,1, -1,0,1, -1,0,1};
    float* out_idx = out + (size_t)8 * 64 * HW;
    float* out_msk = out_idx + (size_t)8 * 18 * HW;

#pragma unroll
    for (int cc = 0; cc < 9; ++cc)
        out_idx[((size_t)b*18 + cc)*HW + p] = hg + kh_i[cc] + om[cc];
#pragma unroll
    for (int cc = 9; cc < 18; ++cc)
        out_idx[((size_t)b*18 + cc)*HW + p] = wg + kw_i[cc-9] + om[cc];

    float mk[9];
#pragma unroll
    for (int kk = 0; kk < 9; ++kk) {
        mk[kk] = 1.0f / (1.0f + __expf(-om[18+kk]));
        out_msk[((size_t)b*9 + kk)*HW + p] = mk[kk];
    }

    // ---------------- Phase 2: modulated deformable conv ----------------
    float acc[64];
#pragma unroll
    for (int o = 0; o < 64; ++o) acc[o] = bias[o];

#pragma unroll
    for (int kk = 0; kk < 9; ++kk) {
        float ph = om[2*kk]   + (float)(kk/3) + (float)(ho - 1);
        float pw = om[2*kk+1] + (float)(kk%3) + (float)(wo - 1);
        float h0f = floorf(ph), w0f = floorf(pw);
        int h0 = (int)h0f, w0 = (int)w0f;
        int h1 = h0 + 1, w1 = w0 + 1;
        float lh = ph - h0f, lw = pw - w0f;
        float hh = 1.0f - lh, hwp = 1.0f - lw;
        float m = mk[kk];
        bool okh0 = (unsigned)h0 < 128u, okh1 = (unsigned)h1 < 128u;
        bool okw0 = (unsigned)w0 < 128u, okw1 = (unsigned)w1 < 128u;
        float w00 = (okh0 && okw0) ? hh*hwp*m : 0.0f;
        float w01 = (okh0 && okw1) ? hh*lw*m  : 0.0f;
        float w10 = (okh1 && okw0) ? lh*hwp*m : 0.0f;
        float w11 = (okh1 && okw1) ? lh*lw*m  : 0.0f;
        int h0c = min(max(h0, 0), 127), h1c = min(max(h1, 0), 127);
        int w0c = min(max(w0, 0), 127), w1c = min(max(w1, 0), 127);
        int o00 = h0c*128 + w0c, o01 = h0c*128 + w1c;
        int o10 = h1c*128 + w0c, o11 = h1c*128 + w1c;

        for (int c = 0; c < 64; ++c) {
            const float* pc = inb + c * HW;
            float col = w00*pc[o00] + w01*pc[o01] + w10*pc[o10] + w11*pc[o11];
#pragma unroll
            for (int o = 0; o < 64; ++o) {
                float w = T ? wmain[(c*9 + kk)*64 + o] : wmain[o*594 + c*9 + kk];
                acc[o] = fmaf(col, w, acc[o]);
            }
        }
        // coordinate channels
        {
            float y0 = h0c * invH, y1 = h1c * invH;
            float x0 = w0c * invH - 0.5f, x1 = w1c * invH - 0.5f;
            float col64 = (w00 + w01)*y0 + (w10 + w11)*y1;
            float col65 = (w00 + w10)*x0 + (w01 + w11)*x1;
#pragma unroll
            for (int o = 0; o < 64; ++o) {
                float wa = T ? wmain[(64*9 + kk)*64 + o] : wmain[o*594 + 64*9 + kk];
                float wb = T ? wmain[(65*9 + kk)*64 + o] : wmain[o*594 + 65*9 + kk];
                acc[o] = fmaf(col64, wa, acc[o]);
                acc[o] = fmaf(col65, wb, acc[o]);
            }
        }
    }

#pragma unroll
    for (int o = 0; o < 64; ++o)
        out[((size_t)b*64 + o)*HW + p] = acc[o];
}

extern "C" void kernel_launch(void* const* d_in, const int* in_sizes, int n_in,
                              void* d_out, int out_size, void* d_ws, size_t ws_size,
                              hipStream_t stream)
{
    const float* input  = (const float*)d_in[0];
    const float* weight = (const float*)d_in[1];
    const float* bias   = (const float*)d_in[2];
    const float* w_om   = (const float*)d_in[3];
    const float* b_om   = (const float*)d_in[4];
    float* out = (float*)d_out;

    dim3 block(64, 4, 1);
    dim3 grid(2, 32, 8);

    size_t need = (size_t)(NW_MAIN + NW_OM) * sizeof(float);
    if (ws_size >= need) {
        float* wt  = (float*)d_ws;
        float* wmt = wt + NW_MAIN;
        transpose_w<<<(NW_MAIN + 255) / 256, 256, 0, stream>>>(weight, w_om, wt, wmt);
        dcn_fused<true><<<grid, block, 0, stream>>>(input, wt, bias, wmt, b_om, out);
    } else {
        dcn_fused<false><<<grid, block, 0, stream>>>(input, weight, bias, w_om, b_om, out);
    }
}

// Round 2
// 433.629 us; speedup vs baseline: 1.1027x; 1.1027x over previous
//
#include <hip/hip_runtime.h>
#include <math.h>

#define HW (128*128)
#define CIN2 66
#define NW_MAIN (594*64)   // transposed main weight  [(c*9+kk)*64 + o]
#define NW_OM   (594*27)   // transposed offset weight [(c*9+i)*27 + oc]

__global__ __launch_bounds__(256) void transpose_w(
    const float* __restrict__ weight, const float* __restrict__ w_om,
    float* __restrict__ wt, float* __restrict__ wmt)
{
    int t = blockIdx.x * 256 + threadIdx.x;
    if (t < NW_MAIN) {
        int o = t & 63, ck = t >> 6;
        wt[t] = weight[o * 594 + ck];
    }
    if (t < NW_OM) {
        int oc = t % 27, ck = t / 27;
        wmt[t] = w_om[oc * 594 + ck];
    }
}

// Fused DCN: block = 64-pixel row segment x 4 o-groups (256 threads).
// Phase A: cooperative offset-mask conv (each wave-group does 1/4 of input
//          channels), 4-way LDS reduction -> offsets/mask in LDS.
// Phase B: per kernel tap, cols[66] computed once into LDS, then GEMM with
//          16 accumulators/thread and wave-uniform scalar weight loads.
__global__ __launch_bounds__(256, 4) void dcn_fused2(
    const float* __restrict__ input,
    const float* __restrict__ wt,     // [(c*9+kk)*64 + o]
    const float* __restrict__ bias,
    const float* __restrict__ wmt,    // [(c*9+i)*27 + oc]
    const float* __restrict__ b_om,
    float* __restrict__ out)
{
    __shared__ float lds_part[4 * 27 * 64];   // 27.0 KB; reused as cols[66*64]
    __shared__ float om_lds[27 * 64];         // 6.75 KB (offsets raw, mask sigmoided)

    const int lane = threadIdx.x & 63;
    const int og   = threadIdx.x >> 6;
    const int ogu  = __builtin_amdgcn_readfirstlane(og);

    const int wo = blockIdx.x * 64 + lane;    // 0..127
    const int ho = blockIdx.y;                // 0..127
    const int b  = blockIdx.z;
    const int p  = ho * 128 + wo;
    const float invH = 1.0f / 128.0f;

    const float* inb = input + (size_t)b * 64 * HW;

    // ---- precompute the 9 fixed-tap addresses / validity (shared by phases)
    int   a9[9];
    float okf[9], vy[9], vx[9];
#pragma unroll
    for (int j = 0; j < 9; ++j) {
        int y = ho - 1 + j / 3;
        int x = wo - 1 + j % 3;
        bool ok = ((unsigned)y < 128u) && ((unsigned)x < 128u);
        int yc = min(max(y, 0), 127), xc = min(max(x, 0), 127);
        a9[j]  = yc * 128 + xc;
        okf[j] = ok ? 1.0f : 0.0f;
        vy[j]  = ok ? y * invH : 0.0f;
        vx[j]  = ok ? (x * invH - 0.5f) : 0.0f;
    }

    const int nc = (ogu < 2) ? 17 : 16;       // channels per o-group (c = ogu + 4*i)

    // ---------------- Phase A: partial offset-mask conv ----------------
    float om_part[27];
#pragma unroll
    for (int oc = 0; oc < 27; ++oc) om_part[oc] = 0.0f;

    for (int i = 0; i < nc; ++i) {
        int c = ogu + 4 * i;
        float v[9];
        if (c < 64) {
            const float* pc = inb + c * HW;
#pragma unroll
            for (int j = 0; j < 9; ++j) v[j] = pc[a9[j]] * okf[j];
        } else if (c == 64) {
#pragma unroll
            for (int j = 0; j < 9; ++j) v[j] = vy[j];
        } else {
#pragma unroll
            for (int j = 0; j < 9; ++j) v[j] = vx[j];
        }
#pragma unroll
        for (int j = 0; j < 9; ++j) {
            const float* wp = wmt + (c * 9 + j) * 27;
#pragma unroll
            for (int oc = 0; oc < 27; ++oc)
                om_part[oc] = fmaf(v[j], wp[oc], om_part[oc]);
        }
    }
#pragma unroll
    for (int oc = 0; oc < 27; ++oc)
        lds_part[(og * 27 + oc) * 64 + lane] = om_part[oc];
    __syncthreads();

    // ---- 4-way reduction + idx/mask outputs (o-group og handles ~7 oc's)
    {
        float* out_idx = out + (size_t)8 * 64 * HW;
        float* out_msk = out_idx + (size_t)8 * 18 * HW;
        const float hg = ho * invH;
        const float wg = wo * invH - 0.5f;
        int oc0 = ogu * 7;
        int noc = (ogu == 3) ? 6 : 7;
        for (int t = 0; t < noc; ++t) {
            int oc = oc0 + t;
            float s = b_om[oc]
                    + lds_part[(0 * 27 + oc) * 64 + lane]
                    + lds_part[(1 * 27 + oc) * 64 + lane]
                    + lds_part[(2 * 27 + oc) * 64 + lane]
                    + lds_part[(3 * 27 + oc) * 64 + lane];
            if (oc < 9) {
                out_idx[((size_t)b * 18 + oc) * HW + p] = hg + (float)(oc / 3 - 1) + s;
                om_lds[oc * 64 + lane] = s;
            } else if (oc < 18) {
                out_idx[((size_t)b * 18 + oc) * HW + p] = wg + (float)((oc - 9) % 3 - 1) + s;
                om_lds[oc * 64 + lane] = s;
            } else {
                float m = 1.0f / (1.0f + __expf(-s));
                out_msk[((size_t)b * 9 + (oc - 18)) * HW + p] = m;
                om_lds[oc * 64 + lane] = m;
            }
        }
    }
    __syncthreads();

    // ---------------- Phase B: modulated deformable conv ----------------
    float* cols = lds_part;   // reuse (66*64 floats)

    float acc[16];
    {
        const float* bp = bias + (ogu << 4);
#pragma unroll
        for (int oi = 0; oi < 16; ++oi) acc[oi] = bp[oi];
    }

    for (int kk = 0; kk < 9; ++kk) {
        float offh = om_lds[(2 * kk) * 64 + lane];
        float offw = om_lds[(2 * kk + 1) * 64 + lane];
        float m    = om_lds[(18 + kk) * 64 + lane];

        float ph = offh + (float)(kk / 3) + (float)(ho - 1);
        float pw = offw + (float)(kk % 3) + (float)(wo - 1);
        float h0f = floorf(ph), w0f = floorf(pw);
        int h0 = (int)h0f, w0 = (int)w0f;
        int h1 = h0 + 1, w1 = w0 + 1;
        float lh = ph - h0f, lw = pw - w0f;
        float hh = 1.0f - lh, hwp = 1.0f - lw;
        bool okh0 = (unsigned)h0 < 128u, okh1 = (unsigned)h1 < 128u;
        bool okw0 = (unsigned)w0 < 128u, okw1 = (unsigned)w1 < 128u;
        float w00 = (okh0 && okw0) ? hh * hwp * m : 0.0f;
        float w01 = (okh0 && okw1) ? hh * lw  * m : 0.0f;
        float w10 = (okh1 && okw0) ? lh * hwp * m : 0.0f;
        float w11 = (okh1 && okw1) ? lh * lw  * m : 0.0f;
        int h0c = min(max(h0, 0), 127), h1c = min(max(h1, 0), 127);
        int w0c = min(max(w0, 0), 127), w1c = min(max(w1, 0), 127);
        int o00 = h0c * 128 + w0c, o01 = h0c * 128 + w1c;
        int o10 = h1c * 128 + w0c, o11 = h1c * 128 + w1c;

        __syncthreads();   // previous GEMM reads done
        for (int i = 0; i < nc; ++i) {
            int c = ogu + 4 * i;
            float col;
            if (c < 64) {
                const float* pc = inb + c * HW;
                col = w00 * pc[o00] + w01 * pc[o01] + w10 * pc[o10] + w11 * pc[o11];
            } else if (c == 64) {
                float y0 = h0c * invH, y1 = h1c * invH;
                col = (w00 + w01) * y0 + (w10 + w11) * y1;
            } else {
                float x0 = w0c * invH - 0.5f, x1 = w1c * invH - 0.5f;
                col = (w00 + w10) * x0 + (w01 + w11) * x1;
            }
            cols[c * 64 + lane] = col;
        }
        __syncthreads();   // cols ready

        for (int c = 0; c < 66; ++c) {
            float colv = cols[c * 64 + lane];
            const float* wp = wt + (c * 9 + kk) * 64 + (ogu << 4);
#pragma unroll
            for (int oi = 0; oi < 16; ++oi)
                acc[oi] = fmaf(colv, wp[oi], acc[oi]);
        }
    }

#pragma unroll
    for (int oi = 0; oi < 16; ++oi)
        out[((size_t)b * 64 + (ogu << 4) + oi) * HW + p] = acc[oi];
}

// ------------------- fallback (no workspace): baseline kernel -------------------
template<bool T>
__global__ __launch_bounds__(256) void dcn_fused(
    const float* __restrict__ input,
    const float* __restrict__ wmain,
    const float* __restrict__ bias,
    const float* __restrict__ wom,
    const float* __restrict__ b_om,
    float* __restrict__ out)
{
    const int wo = blockIdx.x * 64 + threadIdx.x;
    const int ho = blockIdx.y * 4 + threadIdx.y;
    const int b  = blockIdx.z;
    const int p  = ho * 128 + wo;
    const float invH = 1.0f / 128.0f;
    const float* inb = input + (size_t)b * 64 * HW;

    float om[27];
#pragma unroll
    for (int oc = 0; oc < 27; ++oc) om[oc] = b_om[oc];

    for (int c = 0; c < 64; ++c) {
        const float* pc = inb + c * HW;
        float v[9];
#pragma unroll
        for (int kh = 0; kh < 3; ++kh) {
            int y = ho - 1 + kh;
            bool oky = (unsigned)y < 128u;
#pragma unroll
            for (int kw = 0; kw < 3; ++kw) {
                int x = wo - 1 + kw;
                bool ok = oky && ((unsigned)x < 128u);
                v[kh*3+kw] = ok ? pc[y * 128 + x] : 0.0f;
            }
        }
#pragma unroll
        for (int oc = 0; oc < 27; ++oc)
#pragma unroll
            for (int i = 0; i < 9; ++i)
                om[oc] = fmaf(v[i], wom[oc*594 + c*9 + i], om[oc]);
    }
    {
        float v64[9], v65[9];
#pragma unroll
        for (int kh = 0; kh < 3; ++kh) {
            int y = ho - 1 + kh;
            bool oky = (unsigned)y < 128u;
#pragma unroll
            for (int kw = 0; kw < 3; ++kw) {
                int x = wo - 1 + kw;
                bool ok = oky && ((unsigned)x < 128u);
                v64[kh*3+kw] = ok ? y * invH : 0.0f;
                v65[kh*3+kw] = ok ? (x * invH - 0.5f) : 0.0f;
            }
        }
#pragma unroll
        for (int oc = 0; oc < 27; ++oc)
#pragma unroll
            for (int i = 0; i < 9; ++i) {
                om[oc] = fmaf(v64[i], wom[oc*594 + 64*9 + i], om[oc]);
                om[oc] = fmaf(v65[i], wom[oc*594 + 65*9 + i], om[oc]);
            }
    }

    const float hg = ho * invH;
    const float wg = wo * invH - 0.5f;
    float* out_idx = out + (size_t)8 * 64 * HW;
    float* out_msk = out_idx + (size_t)8 * 18 * HW;
#pragma unroll
    for (int cc = 0; cc < 9; ++cc)
        out_idx[((size_t)b*18 + cc)*HW + p] = hg + (float)(cc/3 - 1) + om[cc];
#pragma unroll
    for (int cc = 9; cc < 18; ++cc)
        out_idx[((size_t)b*18 + cc)*HW + p] = wg + (float)((cc-9)%3 - 1) + om[cc];

    float mk[9];
#pragma unroll
    for (int kk = 0; kk < 9; ++kk) {
        mk[kk] = 1.0f / (1.0f + __expf(-om[18+kk]));
        out_msk[((size_t)b*9 + kk)*HW + p] = mk[kk];
    }

    float acc[64];
#pragma unroll
    for (int o = 0; o < 64; ++o) acc[o] = bias[o];

#pragma unroll
    for (int kk = 0; kk < 9; ++kk) {
        float ph = om[2*kk]   + (float)(kk/3) + (float)(ho - 1);
        float pw = om[2*kk+1] + (float)(kk%3) + (float)(wo - 1);
        float h0f = floorf(ph), w0f = floorf(pw);
        int h0 = (int)h0f, w0 = (int)w0f;
        int h1 = h0 + 1, w1 = w0 + 1;
        float lh = ph - h0f, lw = pw - w0f;
        float hh = 1.0f - lh, hwp = 1.0f - lw;
        float m = mk[kk];
        bool okh0 = (unsigned)h0 < 128u, okh1 = (unsigned)h1 < 128u;
        bool okw0 = (unsigned)w0 < 128u, okw1 = (unsigned)w1 < 128u;
        float w00 = (okh0 && okw0) ? hh*hwp*m : 0.0f;
        float w01 = (okh0 && okw1) ? hh*lw*m  : 0.0f;
        float w10 = (okh1 && okw0) ? lh*hwp*m : 0.0f;
        float w11 = (okh1 && okw1) ? lh*lw*m  : 0.0f;
        int h0c = min(max(h0, 0), 127), h1c = min(max(h1, 0), 127);
        int w0c = min(max(w0, 0), 127), w1c = min(max(w1, 0), 127);
        int o00 = h0c*128 + w0c, o01 = h0c*128 + w1c;
        int o10 = h1c*128 + w0c, o11 = h1c*128 + w1c;

        for (int c = 0; c < 64; ++c) {
            const float* pc = inb + c * HW;
            float col = w00*pc[o00] + w01*pc[o01] + w10*pc[o10] + w11*pc[o11];
#pragma unroll
            for (int o = 0; o < 64; ++o)
                acc[o] = fmaf(col, wmain[o*594 + c*9 + kk], acc[o]);
        }
        {
            float y0 = h0c * invH, y1 = h1c * invH;
            float x0 = w0c * invH - 0.5f, x1 = w1c * invH - 0.5f;
            float col64 = (w00 + w01)*y0 + (w10 + w11)*y1;
            float col65 = (w00 + w10)*x0 + (w01 + w11)*x1;
#pragma unroll
            for (int o = 0; o < 64; ++o) {
                acc[o] = fmaf(col64, wmain[o*594 + 64*9 + kk], acc[o]);
                acc[o] = fmaf(col65, wmain[o*594 + 65*9 + kk], acc[o]);
            }
        }
    }

#pragma unroll
    for (int o = 0; o < 64; ++o)
        out[((size_t)b*64 + o)*HW + p] = acc[o];
}

extern "C" void kernel_launch(void* const* d_in, const int* in_sizes, int n_in,
                              void* d_out, int out_size, void* d_ws, size_t ws_size,
                              hipStream_t stream)
{
    const float* input  = (const float*)d_in[0];
    const float* weight = (const float*)d_in[1];
    const float* bias   = (const float*)d_in[2];
    const float* w_om   = (const float*)d_in[3];
    const float* b_om   = (const float*)d_in[4];
    float* out = (float*)d_out;

    size_t need = (size_t)(NW_MAIN + NW_OM) * sizeof(float);
    if (ws_size >= need) {
        float* wt  = (float*)d_ws;
        float* wmt = wt + NW_MAIN;
        transpose_w<<<(NW_MAIN + 255) / 256, 256, 0, stream>>>(weight, w_om, wt, wmt);
        dim3 grid(2, 128, 8);
        dcn_fused2<<<grid, dim3(256, 1, 1), 0, stream>>>(input, wt, bias, wmt, b_om, out);
    } else {
        dim3 grid(2, 32, 8);
        dcn_fused<false><<<grid, dim3(64, 4, 1), 0, stream>>>(input, weight, bias, w_om, b_om, out);
    }
}

// Round 5
// 347.120 us; speedup vs baseline: 1.3776x; 1.2492x over previous
//
#include <hip/hip_runtime.h>
#include <math.h>

#define HW (128*128)

typedef short short8 __attribute__((ext_vector_type(8)));
typedef float floatx4 __attribute__((ext_vector_type(4)));

#define MFMA(a,b,c) __builtin_amdgcn_mfma_f32_16x16x32_bf16((a),(b),(c),0,0,0)

// workspace: [wt2: bf16 main weight 64x864][wmt: fp32 offset weight 594*27]
#define WT2_ELEMS  (64*864)          // [o][kk*96 + c], zero for c>=66
#define WT2_BYTES  (WT2_ELEMS*2)
#define WMT_ELEMS  (594*27)          // [(c*9+j)*27 + oc]
#define WS_NEED    (WT2_BYTES + WMT_ELEMS*4)

static __device__ __forceinline__ unsigned short f2bf(float x) {
    unsigned u = __float_as_uint(x);
    unsigned r = u + 0x7FFFu + ((u >> 16) & 1u);
    return (unsigned short)(r >> 16);
}

__global__ __launch_bounds__(256) void prep_w(
    const float* __restrict__ weight, const float* __restrict__ w_om,
    unsigned short* __restrict__ wt2, float* __restrict__ wmt)
{
    int t = blockIdx.x * 256 + threadIdx.x;
    if (t < WT2_ELEMS) {
        int o = t / 864, k = t % 864;
        int kk = k / 96, c = k % 96;
        float v = (c < 66) ? weight[o * 594 + c * 9 + kk] : 0.0f;
        wt2[t] = f2bf(v);
    } else if (t < WT2_ELEMS + WMT_ELEMS) {
        int t2 = t - WT2_ELEMS;
        int oc = t2 % 27, ck = t2 / 27;
        wmt[t2] = w_om[oc * 594 + ck];
    }
}

// Phase A: fp32 VALU offset conv (round-2-verified path).
// Phase B: cols kept FP32 in LDS (stride 108 floats, single-buffered),
//          converted to bf16 in registers, bf16-MFMA main conv.
__global__ __launch_bounds__(256, 4) void dcn_hybrid2(
    const float* __restrict__ input,
    const unsigned short* __restrict__ wt2,
    const float* __restrict__ bias,
    const float* __restrict__ wmt,
    const float* __restrict__ b_om,
    float* __restrict__ out)
{
    __shared__ __align__(16) float s_red[4 * 27 * 64];   // 6912 floats = 64 rows x 108 in Phase B
    __shared__ float s_offh[9 * 64], s_offw[9 * 64], s_maskf[9 * 64];

    const int tid  = threadIdx.x;
    const int lane = tid & 63;
    const int w    = tid >> 6;
    const int wu   = __builtin_amdgcn_readfirstlane(w);
    const int m15  = lane & 15;
    const int quad = lane >> 4;

    const int wo0 = blockIdx.x * 64;
    const int ho  = blockIdx.y;
    const int b   = blockIdx.z;
    const int wo  = wo0 + lane;
    const int p   = ho * 128 + wo;
    const float invH = 1.0f / 128.0f;

    const float* inb = input + (size_t)b * 64 * HW;

    // ---- 9 fixed-tap addresses / validity for pixel (ho, wo)
    int   a9[9];
    float okf[9], vy[9], vx[9];
#pragma unroll
    for (int j = 0; j < 9; ++j) {
        int y = ho - 1 + j / 3;
        int x = wo - 1 + j % 3;
        bool ok = ((unsigned)y < 128u) && ((unsigned)x < 128u);
        int yc = min(max(y, 0), 127), xc = min(max(x, 0), 127);
        a9[j]  = yc * 128 + xc;
        okf[j] = ok ? 1.0f : 0.0f;
        vy[j]  = ok ? y * invH : 0.0f;
        vx[j]  = ok ? (x * invH - 0.5f) : 0.0f;
    }

    const int nc = (wu < 2) ? 17 : 16;     // channels per wave: c = wu + 4*i

    // ---------------- Phase A: fp32 partial offset conv ----------------
    float om_part[27];
#pragma unroll
    for (int oc = 0; oc < 27; ++oc) om_part[oc] = 0.0f;

    for (int i = 0; i < nc; ++i) {
        int c = wu + 4 * i;
        float v[9];
        if (c < 64) {
            const float* pc = inb + c * HW;
#pragma unroll
            for (int j = 0; j < 9; ++j) v[j] = pc[a9[j]] * okf[j];
        } else if (c == 64) {
#pragma unroll
            for (int j = 0; j < 9; ++j) v[j] = vy[j];
        } else {
#pragma unroll
            for (int j = 0; j < 9; ++j) v[j] = vx[j];
        }
#pragma unroll
        for (int j = 0; j < 9; ++j) {
            const float* wp = wmt + (c * 9 + j) * 27;
#pragma unroll
            for (int oc = 0; oc < 27; ++oc)
                om_part[oc] = fmaf(v[j], wp[oc], om_part[oc]);
        }
    }
#pragma unroll
    for (int oc = 0; oc < 27; ++oc)
        s_red[(w * 27 + oc) * 64 + lane] = om_part[oc];
    __syncthreads();

    // ---- 4-way reduce + idx/mask epilogue + fp32 offsets/mask into LDS
    {
        float* out_idx = out + (size_t)8 * 64 * HW;
        float* out_msk = out_idx + (size_t)8 * 18 * HW;
        const float hg = ho * invH;
        const float wg = wo * invH - 0.5f;
        int oc0 = wu * 7;
        int noc = (wu == 3) ? 6 : 7;
        for (int t = 0; t < noc; ++t) {
            int oc = oc0 + t;
            float s = b_om[oc]
                    + s_red[(0 * 27 + oc) * 64 + lane]
                    + s_red[(1 * 27 + oc) * 64 + lane]
                    + s_red[(2 * 27 + oc) * 64 + lane]
                    + s_red[(3 * 27 + oc) * 64 + lane];
            if (oc < 9) {
                out_idx[((size_t)b * 18 + oc) * HW + p] = hg + (float)(oc / 3 - 1) + s;
                if (oc & 1) s_offw[(oc >> 1) * 64 + lane] = s;
                else        s_offh[(oc >> 1) * 64 + lane] = s;
            } else if (oc < 18) {
                out_idx[((size_t)b * 18 + oc) * HW + p] = wg + (float)((oc - 9) % 3 - 1) + s;
                if (oc & 1) s_offw[(oc >> 1) * 64 + lane] = s;
                else        s_offh[(oc >> 1) * 64 + lane] = s;
            } else {
                float mkv = 1.0f / (1.0f + __expf(-s));
                out_msk[((size_t)b * 9 + (oc - 18)) * HW + p] = mkv;
                s_maskf[(oc - 18) * 64 + lane] = mkv;
            }
        }
    }
    __syncthreads();   // s_red reads done; offsets/mask ready; s_red reusable

    // ---------------- Phase B: fp32 cols in LDS + bf16 MFMA ----------------
    float* s_colf = s_red;   // [64 px][108 floats]

    // zero the K-pad region c in [66,96) (written once, never overwritten)
    for (int z = 0; z < 8; ++z) {
        int cz = 66 + 8 * wu + z;
        if (cz < 96) s_colf[lane * 108 + cz] = 0.0f;
    }

    floatx4 acc[4];
#pragma unroll
    for (int t = 0; t < 4; ++t) acc[t] = (floatx4){0.f, 0.f, 0.f, 0.f};

    for (int kk = 0; kk < 9; ++kk) {
        if (kk) __syncthreads();   // previous MFMA reads done before overwrite

        {   // ---- build fp32 cols for tap kk ----
            float offh = s_offh[kk * 64 + lane];
            float offw = s_offw[kk * 64 + lane];
            float mval = s_maskf[kk * 64 + lane];

            float ph = offh + (float)(kk / 3) + (float)(ho - 1);
            float pw = offw + (float)(kk % 3) + (float)(wo - 1);
            float h0f = floorf(ph), w0f = floorf(pw);
            int h0 = (int)h0f, w0 = (int)w0f;
            int h1 = h0 + 1, w1 = w0 + 1;
            float lh = ph - h0f, lw = pw - w0f;
            float hh = 1.0f - lh, hwp = 1.0f - lw;
            bool okh0 = (unsigned)h0 < 128u, okh1 = (unsigned)h1 < 128u;
            bool okw0 = (unsigned)w0 < 128u, okw1 = (unsigned)w1 < 128u;
            float w00 = (okh0 && okw0) ? hh * hwp * mval : 0.0f;
            float w01 = (okh0 && okw1) ? hh * lw  * mval : 0.0f;
            float w10 = (okh1 && okw0) ? lh * hwp * mval : 0.0f;
            float w11 = (okh1 && okw1) ? lh * lw  * mval : 0.0f;
            int h0c = min(max(h0, 0), 127), h1c = min(max(h1, 0), 127);
            int w0c = min(max(w0, 0), 127), w1c = min(max(w1, 0), 127);
            int o00 = h0c * 128 + w0c, o01 = h0c * 128 + w1c;
            int o10 = h1c * 128 + w0c, o11 = h1c * 128 + w1c;

            float* row = s_colf + lane * 108;
#pragma unroll
            for (int i = 0; i < 8; ++i) {
                int c = wu * 16 + 2 * i;
                const float* p0 = inb + (size_t)c * HW;
                float ca = w00 * p0[o00] + w01 * p0[o01] + w10 * p0[o10] + w11 * p0[o11];
                float cb = w00 * p0[HW + o00] + w01 * p0[HW + o01] + w10 * p0[HW + o10] + w11 * p0[HW + o11];
                row[c]     = ca;
                row[c + 1] = cb;
            }
            if (wu == 3) {
                float y0 = h0c * invH, y1 = h1c * invH;
                float x0 = w0c * invH - 0.5f, x1 = w1c * invH - 0.5f;
                row[64] = (w00 + w01) * y0 + (w10 + w11) * y1;
                row[65] = (w00 + w10) * x0 + (w01 + w11) * x1;
            }
        }
        __syncthreads();   // cols visible to all waves

        short8 A[3];
#pragma unroll
        for (int ks = 0; ks < 3; ++ks)
            A[ks] = *(const short8*)&wt2[(16 * wu + m15) * 864 + kk * 96 + ks * 32 + quad * 8];

#pragma unroll
        for (int t = 0; t < 4; ++t) {
            const float* rowp = s_colf + (16 * t + m15) * 108;
#pragma unroll
            for (int ks = 0; ks < 3; ++ks) {
                const float* fp = rowp + ks * 32 + quad * 8;
                floatx4 f0 = *(const floatx4*)&fp[0];
                floatx4 f1 = *(const floatx4*)&fp[4];
                short8 bf;
                bf[0] = (short)f2bf(f0[0]); bf[1] = (short)f2bf(f0[1]);
                bf[2] = (short)f2bf(f0[2]); bf[3] = (short)f2bf(f0[3]);
                bf[4] = (short)f2bf(f1[0]); bf[5] = (short)f2bf(f1[1]);
                bf[6] = (short)f2bf(f1[2]); bf[7] = (short)f2bf(f1[3]);
                acc[t] = MFMA(A[ks], bf, acc[t]);
            }
        }
    }

    // ---------- Phase B epilogue ----------
    {
        float bs[4];
#pragma unroll
        for (int r = 0; r < 4; ++r) bs[r] = bias[16 * wu + quad * 4 + r];
#pragma unroll
        for (int t = 0; t < 4; ++t) {
            int px = 16 * t + m15;
            size_t pbase = (size_t)ho * 128 + wo0 + px;
#pragma unroll
            for (int r = 0; r < 4; ++r) {
                int o = 16 * wu + quad * 4 + r;
                out[((size_t)b * 64 + o) * HW + pbase] = acc[t][r] + bs[r];
            }
        }
    }
}

// ------------------- fallback (no workspace): fp32 baseline -------------------
__global__ __launch_bounds__(256) void dcn_fb(
    const float* __restrict__ input,
    const float* __restrict__ wmain,
    const float* __restrict__ bias,
    const float* __restrict__ wom,
    const float* __restrict__ b_om,
    float* __restrict__ out)
{
    const int wo = blockIdx.x * 64 + threadIdx.x;
    const int ho = blockIdx.y * 4 + threadIdx.y;
    const int b  = blockIdx.z;
    const int p  = ho * 128 + wo;
    const float invH = 1.0f / 128.0f;
    const float* inb = input + (size_t)b * 64 * HW;

    float om[27];
#pragma unroll
    for (int oc = 0; oc < 27; ++oc) om[oc] = b_om[oc];

    for (int c = 0; c < 64; ++c) {
        const float* pc = inb + c * HW;
        float v[9];
#pragma unroll
        for (int kh = 0; kh < 3; ++kh) {
            int y = ho - 1 + kh;
            bool oky = (unsigned)y < 128u;
#pragma unroll
            for (int kw = 0; kw < 3; ++kw) {
                int x = wo - 1 + kw;
                bool ok = oky && ((unsigned)x < 128u);
                v[kh*3+kw] = ok ? pc[y * 128 + x] : 0.0f;
            }
        }
#pragma unroll
        for (int oc = 0; oc < 27; ++oc)
#pragma unroll
            for (int i = 0; i < 9; ++i)
                om[oc] = fmaf(v[i], wom[oc*594 + c*9 + i], om[oc]);
    }
    {
        float v64[9], v65[9];
#pragma unroll
        for (int kh = 0; kh < 3; ++kh) {
            int y = ho - 1 + kh;
            bool oky = (unsigned)y < 128u;
#pragma unroll
            for (int kw = 0; kw < 3; ++kw) {
                int x = wo - 1 + kw;
                bool ok = oky && ((unsigned)x < 128u);
                v64[kh*3+kw] = ok ? y * invH : 0.0f;
                v65[kh*3+kw] = ok ? (x * invH - 0.5f) : 0.0f;
            }
        }
#pragma unroll
        for (int oc = 0; oc < 27; ++oc)
#pragma unroll
            for (int i = 0; i < 9; ++i) {
                om[oc] = fmaf(v64[i], wom[oc*594 + 64*9 + i], om[oc]);
                om[oc] = fmaf(v65[i], wom[oc*594 + 65*9 + i], om[oc]);
            }
    }

    const float hg = ho * invH;
    const float wg = wo * invH - 0.5f;
    float* out_idx = out + (size_t)8 * 64 * HW;
    float* out_msk = out_idx + (size_t)8 * 18 * HW;
#pragma unroll
    for (int cc = 0; cc < 9; ++cc)
        out_idx[((size_t)b*18 + cc)*HW + p] = hg + (float)(cc/3 - 1) + om[cc];
#pragma unroll
    for (int cc = 9; cc < 18; ++cc)
        out_idx[((size_t)b*18 + cc)*HW + p] = wg + (float)((cc-9)%3 - 1) + om[cc];

    float mk[9];
#pragma unroll
    for (int kk = 0; kk < 9; ++kk) {
        mk[kk] = 1.0f / (1.0f + __expf(-om[18+kk]));
        out_msk[((size_t)b*9 + kk)*HW + p] = mk[kk];
    }

    float acc[64];
#pragma unroll
    for (int o = 0; o < 64; ++o) acc[o] = bias[o];

#pragma unroll
    for (int kk = 0; kk < 9; ++kk) {
        float ph = om[2*kk]   + (float)(kk/3) + (float)(ho - 1);
        float pw = om[2*kk+1] + (float)(kk%3) + (float)(wo - 1);
        float h0f = floorf(ph), w0f = floorf(pw);
        int h0 = (int)h0f, w0 = (int)w0f;
        int h1 = h0 + 1, w1 = w0 + 1;
        float lh = ph - h0f, lw = pw - w0f;
        float hh = 1.0f - lh, hwp = 1.0f - lw;
        float m = mk[kk];
        bool okh0 = (unsigned)h0 < 128u, okh1 = (unsigned)h1 < 128u;
        bool okw0 = (unsigned)w0 < 128u, okw1 = (unsigned)w1 < 128u;
        float w00 = (okh0 && okw0) ? hh*hwp*m : 0.0f;
        float w01 = (okh0 && okw1) ? hh*lw*m  : 0.0f;
        float w10 = (okh1 && okw0) ? lh*hwp*m : 0.0f;
        float w11 = (okh1 && okw1) ? lh*lw*m  : 0.0f;
        int h0c = min(max(h0, 0), 127), h1c = min(max(h1, 0), 127);
        int w0c = min(max(w0, 0), 127), w1c = min(max(w1, 0), 127);
        int o00 = h0c*128 + w0c, o01 = h0c*128 + w1c;
        int o10 = h1c*128 + w0c, o11 = h1c*128 + w1c;

        for (int c = 0; c < 64; ++c) {
            const float* pc = inb + c * HW;
            float col = w00*pc[o00] + w01*pc[o01] + w10*pc[o10] + w11*pc[o11];
#pragma unroll
            for (int o = 0; o < 64; ++o)
                acc[o] = fmaf(col, wmain[o*594 + c*9 + kk], acc[o]);
        }
        {
            float y0 = h0c * invH, y1 = h1c * invH;
            float x0 = w0c * invH - 0.5f, x1 = w1c * invH - 0.5f;
            float col64 = (w00 + w01)*y0 + (w10 + w11)*y1;
            float col65 = (w00 + w10)*x0 + (w01 + w11)*x1;
#pragma unroll
            for (int o = 0; o < 64; ++o) {
                acc[o] = fmaf(col64, wmain[o*594 + 64*9 + kk], acc[o]);
                acc[o] = fmaf(col65, wmain[o*594 + 65*9 + kk], acc[o]);
            }
        }
    }

#pragma unroll
    for (int o = 0; o < 64; ++o)
        out[((size_t)b*64 + o)*HW + p] = acc[o];
}

extern "C" void kernel_launch(void* const* d_in, const int* in_sizes, int n_in,
                              void* d_out, int out_size, void* d_ws, size_t ws_size,
                              hipStream_t stream)
{
    const float* input  = (const float*)d_in[0];
    const float* weight = (const float*)d_in[1];
    const float* bias   = (const float*)d_in[2];
    const float* w_om   = (const float*)d_in[3];
    const float* b_om   = (const float*)d_in[4];
    float* out = (float*)d_out;

    if (ws_size >= (size_t)WS_NEED) {
        unsigned short* wt2 = (unsigned short*)d_ws;
        float* wmt = (float*)((char*)d_ws + WT2_BYTES);
        int total = WT2_ELEMS + WMT_ELEMS;
        prep_w<<<(total + 255) / 256, 256, 0, stream>>>(weight, w_om, wt2, wmt);
        dim3 grid(2, 128, 8);
        dcn_hybrid2<<<grid, dim3(256, 1, 1), 0, stream>>>(input, wt2, bias, wmt, b_om, out);
    } else {
        dim3 grid(2, 32, 8);
        dcn_fb<<<grid, dim3(64, 4, 1), 0, stream>>>(input, weight, bias, w_om, b_om, out);
    }
}